// Round 14
// baseline (209.822 us; speedup 1.0000x reference)
//
#include <hip/hip_runtime.h>
#include <hip/hip_bf16.h>

// Round 14:
//  GEMMs: LDS plane stride re-padded to 524 words == 12 (mod 32) -> staging-write
//         octets sweep all 8 bank groups (r13's 3.7M conflicts: stride==4 mod 32
//         made bank = 4*(skh+row), pairwise collisions). Reads stay 2-way (free).
//  attn:  Qs dropped from LDS (Q A-frags direct from global slab layout, proven
//         in r11) -> 32.5 KB -> 4 blocks/CU, launch_bounds(256,4).
//
// ws layout (r10):
//   [A] qkv_b16: 3072*3840 bf16 (23.6 MB)
//   [B] hs_b   : 3072*1280 bf16 (7.9 MB)  -- reused as attn_b after gemm1
//   [C] qkvw_b : 3840*1280 bf16 (9.8 MB)  -- Qp aliases after gemm1
//   [D] projw_b: 1280*1280 bf16 (3.3 MB)
//   [E] Kp     : 9.4 MB   [F] Vp: 9.4 MB (96-wide, col80 = ones)

#define S_TOT 3072
#define DIM   1280
#define NH    16
#define HD    80
#define SEG   1024
#define TDIM  3840

typedef short v8s __attribute__((ext_vector_type(8)));
typedef float v4f __attribute__((ext_vector_type(4)));

#define PS128 1048  // plane stride (shorts) for 128-row tile: 524 words == 12 mod 32
#define PS64  536   // plane stride for 64-row tile: 268 words == 12 mod 32

__device__ __forceinline__ short f2bf(float v) {
  __hip_bfloat16 b = __float2bfloat16(v);
  return *reinterpret_cast<short*>(&b);
}

__device__ __forceinline__ float bf2f(short s) {
  unsigned u = ((unsigned)(unsigned short)s) << 16;
  float f;
  __builtin_memcpy(&f, &u, 4);
  return f;
}

#define CVT_N1 (S_TOT * DIM / 4)
#define CVT_N2 (TDIM * DIM / 4)
#define CVT_N3 (DIM * DIM / 4)
__global__ __launch_bounds__(256) void cvt3(const float* __restrict__ in1,
                                            const float* __restrict__ in2,
                                            const float* __restrict__ in3,
                                            __hip_bfloat16* __restrict__ o1,
                                            __hip_bfloat16* __restrict__ o2,
                                            __hip_bfloat16* __restrict__ o3) {
  int i = blockIdx.x * 256 + threadIdx.x;
  const float* in;
  __hip_bfloat16* out;
  if (i < CVT_N1) { in = in1; out = o1; }
  else if (i < CVT_N1 + CVT_N2) { in = in2; out = o2; i -= CVT_N1; }
  else { in = in3; out = o3; i -= CVT_N1 + CVT_N2; }
  const float4 v = ((const float4*)in)[i];
  __hip_bfloat162 p0, p1;
  p0.x = __float2bfloat16(v.x); p0.y = __float2bfloat16(v.y);
  p1.x = __float2bfloat16(v.z); p1.y = __float2bfloat16(v.w);
  __hip_bfloat162* o = (__hip_bfloat162*)(out + (size_t)i * 4);
  o[0] = p0; o[1] = p1;
}

// ---------------- gemm1: 128x128, BK=64, coalesced staging ----------------
__global__ __launch_bounds__(256) void gemm1_c(const __hip_bfloat16* __restrict__ A,
                                               const __hip_bfloat16* __restrict__ B,
                                               const float* __restrict__ bias,
                                               __hip_bfloat16* __restrict__ C,
                                               int M, int N, int K) {
  __shared__ __align__(16) short Abuf[2][8 * PS128];
  __shared__ __align__(16) short Bbuf[2][8 * PS128];
  const int tid  = threadIdx.x;
  const int wave = tid >> 6;
  const int lane = tid & 63;
  const int quad = lane >> 4;
  const int l16  = lane & 15;
  const int bm = blockIdx.x * 128;   // M fastest: consecutive blocks share B
  const int bn = blockIdx.y * 128;
  const int wm = (wave >> 1) * 64;
  const int wn = (wave & 1) * 64;

  const int srow = tid >> 3;
  const int skh  = tid & 7;
  const __hip_bfloat16* Ag[4];
  const __hip_bfloat16* Bg[4];
  int Ao[4], Bo[4];
  #pragma unroll
  for (int l = 0; l < 4; ++l) {
    const int row = l * 32 + srow;
    Ag[l] = A + (size_t)(bm + row) * K + skh * 8;
    Bg[l] = B + (size_t)(bn + row) * K + skh * 8;
    Ao[l] = skh * PS128 + row * 8;
    Bo[l] = skh * PS128 + row * 8;
  }

  v4f acc[4][4];
  const v4f vz = {0.f, 0.f, 0.f, 0.f};
  #pragma unroll
  for (int i = 0; i < 4; ++i)
    #pragma unroll
    for (int j = 0; j < 4; ++j) acc[i][j] = vz;

  const int nk = K >> 6;  // 20 slabs of 64
  v8s ra[4], rb[4];

  #pragma unroll
  for (int l = 0; l < 4; ++l) { ra[l] = *(const v8s*)Ag[l]; rb[l] = *(const v8s*)Bg[l]; }
  #pragma unroll
  for (int l = 0; l < 4; ++l) {
    *(v8s*)&Abuf[0][Ao[l]] = ra[l];
    *(v8s*)&Bbuf[0][Bo[l]] = rb[l];
  }
  __syncthreads();

  for (int k = 0; k < nk; ++k) {
    const int cur = k & 1;
    const bool more = (k + 1 < nk);
    if (more) {
      const int off = (k + 1) * 64;
      #pragma unroll
      for (int l = 0; l < 4; ++l) {
        ra[l] = *(const v8s*)(Ag[l] + off);
        rb[l] = *(const v8s*)(Bg[l] + off);
      }
    }
    #pragma unroll
    for (int s = 0; s < 2; ++s) {
      v8s af[4], bf[4];
      #pragma unroll
      for (int i = 0; i < 4; ++i) {
        af[i] = *(const v8s*)&Abuf[cur][(s * 4 + quad) * PS128 + (wm + i * 16 + l16) * 8];
        bf[i] = *(const v8s*)&Bbuf[cur][(s * 4 + quad) * PS128 + (wn + i * 16 + l16) * 8];
      }
      #pragma unroll
      for (int i = 0; i < 4; ++i)
        #pragma unroll
        for (int j = 0; j < 4; ++j)
          acc[i][j] = __builtin_amdgcn_mfma_f32_16x16x32_bf16(af[i], bf[j], acc[i][j], 0, 0, 0);
    }
    if (more) {
      #pragma unroll
      for (int l = 0; l < 4; ++l) {
        *(v8s*)&Abuf[1 - cur][Ao[l]] = ra[l];
        *(v8s*)&Bbuf[1 - cur][Bo[l]] = rb[l];
      }
    }
    __syncthreads();
  }

  #pragma unroll
  for (int j = 0; j < 4; ++j) {
    const int col = bn + wn + j * 16 + l16;
    const float bj = bias[col];
    #pragma unroll
    for (int i = 0; i < 4; ++i) {
      const int row0 = bm + wm + i * 16 + quad * 4;
      #pragma unroll
      for (int r = 0; r < 4; ++r)
        C[(size_t)(row0 + r) * N + col] = __float2bfloat16(acc[i][j][r] + bj);
    }
  }
}

// ---------------- gemm2: 64x128, BK=64, coalesced staging, fp32 out ----------
__global__ __launch_bounds__(256) void gemm2_c(const __hip_bfloat16* __restrict__ A,
                                               const __hip_bfloat16* __restrict__ B,
                                               const float* __restrict__ bias,
                                               float* __restrict__ C,
                                               int M, int N, int K) {
  __shared__ __align__(16) short Abuf[2][8 * PS64];
  __shared__ __align__(16) short Bbuf[2][8 * PS128];
  const int tid  = threadIdx.x;
  const int wave = tid >> 6;
  const int lane = tid & 63;
  const int quad = lane >> 4;
  const int l16  = lane & 15;
  const int bm = blockIdx.x * 64;    // M fastest
  const int bn = blockIdx.y * 128;
  const int wm = (wave & 1) * 32;
  const int wn = (wave >> 1) * 64;

  const int srow = tid >> 3;
  const int skh  = tid & 7;
  const __hip_bfloat16* Ag[2];
  const __hip_bfloat16* Bg[4];
  int Ao[2], Bo[4];
  #pragma unroll
  for (int l = 0; l < 2; ++l) {
    const int row = l * 32 + srow;
    Ag[l] = A + (size_t)(bm + row) * K + skh * 8;
    Ao[l] = skh * PS64 + row * 8;
  }
  #pragma unroll
  for (int l = 0; l < 4; ++l) {
    const int row = l * 32 + srow;
    Bg[l] = B + (size_t)(bn + row) * K + skh * 8;
    Bo[l] = skh * PS128 + row * 8;
  }

  v4f acc[2][4];
  const v4f vz = {0.f, 0.f, 0.f, 0.f};
  #pragma unroll
  for (int i = 0; i < 2; ++i)
    #pragma unroll
    for (int j = 0; j < 4; ++j) acc[i][j] = vz;

  const int nk = K >> 6;
  v8s ra[2], rb[4];

  #pragma unroll
  for (int l = 0; l < 2; ++l) ra[l] = *(const v8s*)Ag[l];
  #pragma unroll
  for (int l = 0; l < 4; ++l) rb[l] = *(const v8s*)Bg[l];
  #pragma unroll
  for (int l = 0; l < 2; ++l) *(v8s*)&Abuf[0][Ao[l]] = ra[l];
  #pragma unroll
  for (int l = 0; l < 4; ++l) *(v8s*)&Bbuf[0][Bo[l]] = rb[l];
  __syncthreads();

  for (int k = 0; k < nk; ++k) {
    const int cur = k & 1;
    const bool more = (k + 1 < nk);
    if (more) {
      const int off = (k + 1) * 64;
      #pragma unroll
      for (int l = 0; l < 2; ++l) ra[l] = *(const v8s*)(Ag[l] + off);
      #pragma unroll
      for (int l = 0; l < 4; ++l) rb[l] = *(const v8s*)(Bg[l] + off);
    }
    #pragma unroll
    for (int s = 0; s < 2; ++s) {
      v8s af[2], bf[4];
      #pragma unroll
      for (int i = 0; i < 2; ++i)
        af[i] = *(const v8s*)&Abuf[cur][(s * 4 + quad) * PS64 + (wm + i * 16 + l16) * 8];
      #pragma unroll
      for (int j = 0; j < 4; ++j)
        bf[j] = *(const v8s*)&Bbuf[cur][(s * 4 + quad) * PS128 + (wn + j * 16 + l16) * 8];
      #pragma unroll
      for (int i = 0; i < 2; ++i)
        #pragma unroll
        for (int j = 0; j < 4; ++j)
          acc[i][j] = __builtin_amdgcn_mfma_f32_16x16x32_bf16(af[i], bf[j], acc[i][j], 0, 0, 0);
    }
    if (more) {
      #pragma unroll
      for (int l = 0; l < 2; ++l) *(v8s*)&Abuf[1 - cur][Ao[l]] = ra[l];
      #pragma unroll
      for (int l = 0; l < 4; ++l) *(v8s*)&Bbuf[1 - cur][Bo[l]] = rb[l];
    }
    __syncthreads();
  }

  #pragma unroll
  for (int j = 0; j < 4; ++j) {
    const int col = bn + wn + j * 16 + l16;
    const float bj = bias[col];
    #pragma unroll
    for (int i = 0; i < 2; ++i) {
      const int row0 = bm + wm + i * 16 + quad * 4;
      #pragma unroll
      for (int r = 0; r < 4; ++r)
        C[(size_t)(row0 + r) * N + col] = acc[i][j][r] + bj;
    }
  }
}

// ---------------- merged pack kernel (unchanged) ----------------
#define QK_BLOCKS ((2 * S_TOT * 16 * 12) / 256)   // 4608
#define V_BLOCKS  ((3 * 16 * 16 * 8 * 96) / 256)  // 2304
__global__ __launch_bounds__(256) void pack_all(const __hip_bfloat16* __restrict__ qkv,
                                                const float* __restrict__ cos_,
                                                const float* __restrict__ sin_,
                                                short* __restrict__ Qp,
                                                short* __restrict__ Kp,
                                                short* __restrict__ Vp) {
  const int bid = blockIdx.x;
  if (bid < QK_BLOCKS) {
    const int idx = bid * 256 + threadIdx.x;
    const int kd = idx % 12;
    const int h  = (idx / 12) % 16;
    const int s  = (idx / 192) % S_TOT;
    const int p  = idx / (192 * S_TOT);
    const int seg = s >> 10, tb = (s >> 6) & 15, t = s & 63;
    short* out = (p ? Kp : Qp) +
                 ((size_t)(((seg * 16 + h) * 16 + tb) * 12 + kd) * 64 + t) * 8;
    short tmp[8];
    if (kd >= 10) {
      #pragma unroll
      for (int j = 0; j < 8; ++j) tmp[j] = 0;
      *(int4*)out = *(int4*)tmp;
      return;
    }
    const short* row = (const short*)qkv + (size_t)s * TDIM + p * DIM + h * HD;
    const int d0 = kd * 8;
    const v8s xm = *(const v8s*)(row + d0);
    const v8s xr = *(const v8s*)(row + d0 + ((kd < 5) ? 40 : -40));
    const float sgn = (kd < 5) ? -1.f : 1.f;
    const float scale = (p == 0) ? 0.111803398874989485f : 1.0f;
    #pragma unroll
    for (int j = 0; j < 8; ++j) {
      const int d = d0 + j;
      const float v = (bf2f(xm[j]) * cos_[s * HD + d] +
                       sgn * bf2f(xr[j]) * sin_[s * HD + d]) * scale;
      tmp[j] = f2bf(v);
    }
    *(int4*)out = *(int4*)tmp;
  } else {
    const int idx = (bid - QK_BLOCKS) * 256 + threadIdx.x;
    const int d  = idx % 96;
    const int td = (idx / 96) % 8;
    const int tb = (idx / 768) % 16;
    const int h  = (idx / (768 * 16)) % 16;
    const int seg = idx / (768 * 256);
    const int s0 = seg * SEG + tb * 64 + td * 8;
    const short* q = (const short*)qkv;
    short tmp[8];
    if (d < 80) {
      #pragma unroll
      for (int j = 0; j < 8; ++j)
        tmp[j] = q[(size_t)(s0 + j) * TDIM + 2 * DIM + h * HD + d];
    } else {
      const short fill = (d == 80) ? (short)0x3F80 : (short)0;
      #pragma unroll
      for (int j = 0; j < 8; ++j) tmp[j] = fill;
    }
    *(int4*)(Vp + (size_t)idx * 8) = *(int4*)tmp;
  }
}

// ---------------- fused flash MFMA attention: Q direct from global ------------
// LDS = Ks 12 + Vs 12 + Ps 8.5 = 32.5 KB -> 4 blocks/CU.
__global__ __launch_bounds__(256, 4) void attn_mfma(const short* __restrict__ Qp,
                                                    const short* __restrict__ Kp,
                                                    const short* __restrict__ Vp,
                                                    __hip_bfloat16* __restrict__ out) {
  __shared__ __align__(16) short Ks[64 * 96];
  __shared__ __align__(16) short Vs[64 * 96];
  __shared__ __align__(16) short Ps[4][16 * 68];

  const int qt  = blockIdx.x;
  const int h   = blockIdx.y;
  const int seg = blockIdx.z;
  const int tid  = threadIdx.x;
  const int wave = tid >> 6;
  const int lane = tid & 63;
  const int quad = lane >> 4;
  const int l16  = lane & 15;
  const int sh16 = seg * 16 + h;

  const short* Qg = Qp + (size_t)(sh16 * 16 + qt) * 6144;
  const short* Kg = Kp + (size_t)sh16 * 16 * 6144;
  const short* Vg = Vp + (size_t)sh16 * 16 * 6144;

  // Q A-frags straight from global (slab layout == LDS image; proven in r11)
  v8s af[3];
  #pragma unroll
  for (int ks = 0; ks < 3; ++ks)
    af[ks] = *(const v8s*)(Qg + ((ks * 4 + quad) * 64 + wave * 16 + l16) * 8);

  v8s kr[3], vr[3];
  #pragma unroll
  for (int it = 0; it < 3; ++it) {
    const int o = (it * 256 + tid) * 8;
    kr[it] = *(const v8s*)(Kg + o);
    vr[it] = *(const v8s*)(Vg + o);
  }
  #pragma unroll
  for (int it = 0; it < 3; ++it) {
    const int o = (it * 256 + tid) * 8;
    *(v8s*)&Ks[o] = kr[it];
    *(v8s*)&Vs[o] = vr[it];
  }
  __syncthreads();

  v4f o4[6];
  const v4f vz = {0.f, 0.f, 0.f, 0.f};
  #pragma unroll
  for (int n = 0; n < 6; ++n) o4[n] = vz;

  for (int kb = 0; kb < 16; ++kb) {
    const bool more = (kb + 1 < 16);
    if (more) {
      const size_t base = (size_t)(kb + 1) * 6144;
      #pragma unroll
      for (int it = 0; it < 3; ++it) {
        const int o = (it * 256 + tid) * 8;
        kr[it] = *(const v8s*)(Kg + base + o);
        vr[it] = *(const v8s*)(Vg + base + o);
      }
    }

    v4f s4[4];
    #pragma unroll
    for (int j = 0; j < 4; ++j) {
      s4[j] = vz;
      #pragma unroll
      for (int ks = 0; ks < 3; ++ks) {
        const v8s bf = *(const v8s*)&Ks[((ks * 4 + quad) * 64 + j * 16 + l16) * 8];
        s4[j] = __builtin_amdgcn_mfma_f32_16x16x32_bf16(af[ks], bf, s4[j], 0, 0, 0);
      }
    }

    #pragma unroll
    for (int reg = 0; reg < 4; ++reg)
      #pragma unroll
      for (int j = 0; j < 4; ++j)
        Ps[wave][(quad * 4 + reg) * 68 + j * 16 + l16] = f2bf(__expf(s4[j][reg]));

    v8s pa[2];
    #pragma unroll
    for (int kp = 0; kp < 2; ++kp)
      pa[kp] = *(const v8s*)&Ps[wave][l16 * 68 + kp * 32 + quad * 8];
    #pragma unroll
    for (int n = 0; n < 6; ++n) {
      #pragma unroll
      for (int kp = 0; kp < 2; ++kp) {
        const v8s vb = *(const v8s*)&Vs[((kp * 4 + quad) * 96 + n * 16 + l16) * 8];
        o4[n] = __builtin_amdgcn_mfma_f32_16x16x32_bf16(pa[kp], vb, o4[n], 0, 0, 0);
      }
    }

    __syncthreads();
    if (more) {
      #pragma unroll
      for (int it = 0; it < 3; ++it) {
        const int o = (it * 256 + tid) * 8;
        *(v8s*)&Ks[o] = kr[it];
        *(v8s*)&Vs[o] = vr[it];
      }
    }
    __syncthreads();
  }

  float inv[4];
  #pragma unroll
  for (int r = 0; r < 4; ++r)
    inv[r] = 1.f / __shfl(o4[5][r], quad << 4);
  const int row0 = seg * SEG + qt * 64 + wave * 16 + quad * 4;
  #pragma unroll
  for (int n = 0; n < 5; ++n) {
    const int col = h * HD + n * 16 + l16;
    #pragma unroll
    for (int r = 0; r < 4; ++r)
      out[(size_t)(row0 + r) * DIM + col] = __float2bfloat16(o4[n][r] * inv[r]);
  }
}

extern "C" void kernel_launch(void* const* d_in, const int* in_sizes, int n_in,
                              void* d_out, int out_size, void* d_ws, size_t ws_size,
                              hipStream_t stream) {
  (void)in_sizes; (void)n_in; (void)out_size; (void)ws_size;
  const float* hs     = (const float*)d_in[0];
  const float* cosp   = (const float*)d_in[1];
  const float* sinp   = (const float*)d_in[2];
  const float* qkv_w  = (const float*)d_in[3];
  const float* qkv_b  = (const float*)d_in[4];
  const float* proj_w = (const float*)d_in[5];
  const float* proj_b = (const float*)d_in[6];

  float* out_f = (float*)d_out;
  __hip_bfloat16* qkv_b16 = (__hip_bfloat16*)d_ws;                     // [A]
  __hip_bfloat16* hs_b    = qkv_b16 + (size_t)S_TOT * TDIM;            // [B]
  __hip_bfloat16* qkvw_b  = hs_b + (size_t)S_TOT * DIM;                // [C]
  __hip_bfloat16* projw_b = qkvw_b + (size_t)TDIM * DIM;               // [D]
  short* Qp = (short*)qkvw_b;                                          // alias [C]
  short* Kp = (short*)(projw_b + (size_t)DIM * DIM);                   // [E]
  short* Vp = Kp + (size_t)3 * 16 * 16 * 6144;                         // [F]
  __hip_bfloat16* attn_b = hs_b;                                       // alias [B]

  cvt3<<<(CVT_N1 + CVT_N2 + CVT_N3) / 256, 256, 0, stream>>>(
      hs, qkv_w, proj_w, hs_b, qkvw_b, projw_b);

  gemm1_c<<<dim3(S_TOT / 128, TDIM / 128), 256, 0, stream>>>(
      hs_b, qkvw_b, qkv_b, qkv_b16, S_TOT, TDIM, DIM);

  pack_all<<<QK_BLOCKS + V_BLOCKS, 256, 0, stream>>>(qkv_b16, cosp, sinp, Qp, Kp, Vp);

  attn_mfma<<<dim3(16, NH, 3), 256, 0, stream>>>(Qp, Kp, Vp, attn_b);

  gemm2_c<<<dim3(S_TOT / 64, DIM / 128), 256, 0, stream>>>(
      attn_b, projw_b, proj_b, out_f, S_TOT, DIM, DIM);
}

// Round 15
// 208.145 us; speedup vs baseline: 1.0081x; 1.0081x over previous
//
#include <hip/hip_runtime.h>
#include <hip/hip_bf16.h>

// Round 15: XOR-swizzled LDS layout for GEMM staging. r13/r14's 3.69M bank
// conflicts came from the scattered octet WRITE (lane octets hitting 8 kh-planes;
// b128 phasing collides 2-way; padding can't fix a scatter). Swizzle: chunk
// (row,kh) at (row*8 + (kh ^ (row&7)))*8 shorts -> octet writes are contiguous
// 128 B (r6/r10's proven zero-conflict pattern); reads keep the zero-conflict
// bank-start structure. No padding: 16 KB/buffer exact. Everything else = r14.
//
// ws layout (r10):
//   [A] qkv_b16: 3072*3840 bf16 (23.6 MB)
//   [B] hs_b   : 3072*1280 bf16 (7.9 MB)  -- reused as attn_b after gemm1
//   [C] qkvw_b : 3840*1280 bf16 (9.8 MB)  -- Qp aliases after gemm1
//   [D] projw_b: 1280*1280 bf16 (3.3 MB)
//   [E] Kp     : 9.4 MB   [F] Vp: 9.4 MB (96-wide, col80 = ones)

#define S_TOT 3072
#define DIM   1280
#define NH    16
#define HD    80
#define SEG   1024
#define TDIM  3840

typedef short v8s __attribute__((ext_vector_type(8)));
typedef float v4f __attribute__((ext_vector_type(4)));

__device__ __forceinline__ short f2bf(float v) {
  __hip_bfloat16 b = __float2bfloat16(v);
  return *reinterpret_cast<short*>(&b);
}

__device__ __forceinline__ float bf2f(short s) {
  unsigned u = ((unsigned)(unsigned short)s) << 16;
  float f;
  __builtin_memcpy(&f, &u, 4);
  return f;
}

#define CVT_N1 (S_TOT * DIM / 4)
#define CVT_N2 (TDIM * DIM / 4)
#define CVT_N3 (DIM * DIM / 4)
__global__ __launch_bounds__(256) void cvt3(const float* __restrict__ in1,
                                            const float* __restrict__ in2,
                                            const float* __restrict__ in3,
                                            __hip_bfloat16* __restrict__ o1,
                                            __hip_bfloat16* __restrict__ o2,
                                            __hip_bfloat16* __restrict__ o3) {
  int i = blockIdx.x * 256 + threadIdx.x;
  const float* in;
  __hip_bfloat16* out;
  if (i < CVT_N1) { in = in1; out = o1; }
  else if (i < CVT_N1 + CVT_N2) { in = in2; out = o2; i -= CVT_N1; }
  else { in = in3; out = o3; i -= CVT_N1 + CVT_N2; }
  const float4 v = ((const float4*)in)[i];
  __hip_bfloat162 p0, p1;
  p0.x = __float2bfloat16(v.x); p0.y = __float2bfloat16(v.y);
  p1.x = __float2bfloat16(v.z); p1.y = __float2bfloat16(v.w);
  __hip_bfloat162* o = (__hip_bfloat162*)(out + (size_t)i * 4);
  o[0] = p0; o[1] = p1;
}

// ---------------- gemm1: 128x128, BK=64, coalesced staging + XOR swizzle -------
// LDS chunk (row, kh) at shorts offset (row*8 + (kh ^ (row&7))) * 8.
__global__ __launch_bounds__(256) void gemm1_c(const __hip_bfloat16* __restrict__ A,
                                               const __hip_bfloat16* __restrict__ B,
                                               const float* __restrict__ bias,
                                               __hip_bfloat16* __restrict__ C,
                                               int M, int N, int K) {
  __shared__ __align__(16) short Abuf[2][8192];  // 16 KB each
  __shared__ __align__(16) short Bbuf[2][8192];
  const int tid  = threadIdx.x;
  const int wave = tid >> 6;
  const int lane = tid & 63;
  const int quad = lane >> 4;
  const int l16  = lane & 15;
  const int bm = blockIdx.x * 128;   // M fastest: consecutive blocks share B
  const int bn = blockIdx.y * 128;
  const int wm = (wave >> 1) * 64;
  const int wn = (wave & 1) * 64;

  const int srow = tid >> 3;
  const int skh  = tid & 7;
  const __hip_bfloat16* Ag[4];
  const __hip_bfloat16* Bg[4];
  int So[4];
  #pragma unroll
  for (int l = 0; l < 4; ++l) {
    const int row = l * 32 + srow;
    Ag[l] = A + (size_t)(bm + row) * K + skh * 8;
    Bg[l] = B + (size_t)(bn + row) * K + skh * 8;
    So[l] = (row * 8 + (skh ^ (row & 7))) * 8;   // swizzled chunk offset
  }

  v4f acc[4][4];
  const v4f vz = {0.f, 0.f, 0.f, 0.f};
  #pragma unroll
  for (int i = 0; i < 4; ++i)
    #pragma unroll
    for (int j = 0; j < 4; ++j) acc[i][j] = vz;

  const int sw = l16 & 7;  // read-side swizzle key (row&7 == l16&7)
  const int nk = K >> 6;   // 20 slabs of 64
  v8s ra[4], rb[4];

  #pragma unroll
  for (int l = 0; l < 4; ++l) { ra[l] = *(const v8s*)Ag[l]; rb[l] = *(const v8s*)Bg[l]; }
  #pragma unroll
  for (int l = 0; l < 4; ++l) {
    *(v8s*)&Abuf[0][So[l]] = ra[l];
    *(v8s*)&Bbuf[0][So[l]] = rb[l];
  }
  __syncthreads();

  for (int k = 0; k < nk; ++k) {
    const int cur = k & 1;
    const bool more = (k + 1 < nk);
    if (more) {
      const int off = (k + 1) * 64;
      #pragma unroll
      for (int l = 0; l < 4; ++l) {
        ra[l] = *(const v8s*)(Ag[l] + off);
        rb[l] = *(const v8s*)(Bg[l] + off);
      }
    }
    #pragma unroll
    for (int s = 0; s < 2; ++s) {
      const int khx = (s * 4 + quad) ^ sw;
      v8s af[4], bf[4];
      #pragma unroll
      for (int i = 0; i < 4; ++i) {
        af[i] = *(const v8s*)&Abuf[cur][((wm + i * 16 + l16) * 8 + khx) * 8];
        bf[i] = *(const v8s*)&Bbuf[cur][((wn + i * 16 + l16) * 8 + khx) * 8];
      }
      #pragma unroll
      for (int i = 0; i < 4; ++i)
        #pragma unroll
        for (int j = 0; j < 4; ++j)
          acc[i][j] = __builtin_amdgcn_mfma_f32_16x16x32_bf16(af[i], bf[j], acc[i][j], 0, 0, 0);
    }
    if (more) {
      #pragma unroll
      for (int l = 0; l < 4; ++l) {
        *(v8s*)&Abuf[1 - cur][So[l]] = ra[l];
        *(v8s*)&Bbuf[1 - cur][So[l]] = rb[l];
      }
    }
    __syncthreads();
  }

  #pragma unroll
  for (int j = 0; j < 4; ++j) {
    const int col = bn + wn + j * 16 + l16;
    const float bj = bias[col];
    #pragma unroll
    for (int i = 0; i < 4; ++i) {
      const int row0 = bm + wm + i * 16 + quad * 4;
      #pragma unroll
      for (int r = 0; r < 4; ++r)
        C[(size_t)(row0 + r) * N + col] = __float2bfloat16(acc[i][j][r] + bj);
    }
  }
}

// ---------------- gemm2: 64x128, BK=64, coalesced + swizzle, fp32 out ----------
__global__ __launch_bounds__(256) void gemm2_c(const __hip_bfloat16* __restrict__ A,
                                               const __hip_bfloat16* __restrict__ B,
                                               const float* __restrict__ bias,
                                               float* __restrict__ C,
                                               int M, int N, int K) {
  __shared__ __align__(16) short Abuf[2][4096];  // 8 KB each
  __shared__ __align__(16) short Bbuf[2][8192];  // 16 KB each
  const int tid  = threadIdx.x;
  const int wave = tid >> 6;
  const int lane = tid & 63;
  const int quad = lane >> 4;
  const int l16  = lane & 15;
  const int bm = blockIdx.x * 64;    // M fastest
  const int bn = blockIdx.y * 128;
  const int wm = (wave & 1) * 32;
  const int wn = (wave >> 1) * 64;

  const int srow = tid >> 3;
  const int skh  = tid & 7;
  const __hip_bfloat16* Ag[2];
  const __hip_bfloat16* Bg[4];
  int Ao[2], Bo[4];
  #pragma unroll
  for (int l = 0; l < 2; ++l) {
    const int row = l * 32 + srow;
    Ag[l] = A + (size_t)(bm + row) * K + skh * 8;
    Ao[l] = (row * 8 + (skh ^ (row & 7))) * 8;
  }
  #pragma unroll
  for (int l = 0; l < 4; ++l) {
    const int row = l * 32 + srow;
    Bg[l] = B + (size_t)(bn + row) * K + skh * 8;
    Bo[l] = (row * 8 + (skh ^ (row & 7))) * 8;
  }

  v4f acc[2][4];
  const v4f vz = {0.f, 0.f, 0.f, 0.f};
  #pragma unroll
  for (int i = 0; i < 2; ++i)
    #pragma unroll
    for (int j = 0; j < 4; ++j) acc[i][j] = vz;

  const int sw = l16 & 7;
  const int nk = K >> 6;
  v8s ra[2], rb[4];

  #pragma unroll
  for (int l = 0; l < 2; ++l) ra[l] = *(const v8s*)Ag[l];
  #pragma unroll
  for (int l = 0; l < 4; ++l) rb[l] = *(const v8s*)Bg[l];
  #pragma unroll
  for (int l = 0; l < 2; ++l) *(v8s*)&Abuf[0][Ao[l]] = ra[l];
  #pragma unroll
  for (int l = 0; l < 4; ++l) *(v8s*)&Bbuf[0][Bo[l]] = rb[l];
  __syncthreads();

  for (int k = 0; k < nk; ++k) {
    const int cur = k & 1;
    const bool more = (k + 1 < nk);
    if (more) {
      const int off = (k + 1) * 64;
      #pragma unroll
      for (int l = 0; l < 2; ++l) ra[l] = *(const v8s*)(Ag[l] + off);
      #pragma unroll
      for (int l = 0; l < 4; ++l) rb[l] = *(const v8s*)(Bg[l] + off);
    }
    #pragma unroll
    for (int s = 0; s < 2; ++s) {
      const int khx = (s * 4 + quad) ^ sw;
      v8s af[2], bf[4];
      #pragma unroll
      for (int i = 0; i < 2; ++i)
        af[i] = *(const v8s*)&Abuf[cur][((wm + i * 16 + l16) * 8 + khx) * 8];
      #pragma unroll
      for (int j = 0; j < 4; ++j)
        bf[j] = *(const v8s*)&Bbuf[cur][((wn + j * 16 + l16) * 8 + khx) * 8];
      #pragma unroll
      for (int i = 0; i < 2; ++i)
        #pragma unroll
        for (int j = 0; j < 4; ++j)
          acc[i][j] = __builtin_amdgcn_mfma_f32_16x16x32_bf16(af[i], bf[j], acc[i][j], 0, 0, 0);
    }
    if (more) {
      #pragma unroll
      for (int l = 0; l < 2; ++l) *(v8s*)&Abuf[1 - cur][Ao[l]] = ra[l];
      #pragma unroll
      for (int l = 0; l < 4; ++l) *(v8s*)&Bbuf[1 - cur][Bo[l]] = rb[l];
    }
    __syncthreads();
  }

  #pragma unroll
  for (int j = 0; j < 4; ++j) {
    const int col = bn + wn + j * 16 + l16;
    const float bj = bias[col];
    #pragma unroll
    for (int i = 0; i < 2; ++i) {
      const int row0 = bm + wm + i * 16 + quad * 4;
      #pragma unroll
      for (int r = 0; r < 4; ++r)
        C[(size_t)(row0 + r) * N + col] = acc[i][j][r] + bj;
    }
  }
}

// ---------------- merged pack kernel (unchanged) ----------------
#define QK_BLOCKS ((2 * S_TOT * 16 * 12) / 256)   // 4608
#define V_BLOCKS  ((3 * 16 * 16 * 8 * 96) / 256)  // 2304
__global__ __launch_bounds__(256) void pack_all(const __hip_bfloat16* __restrict__ qkv,
                                                const float* __restrict__ cos_,
                                                const float* __restrict__ sin_,
                                                short* __restrict__ Qp,
                                                short* __restrict__ Kp,
                                                short* __restrict__ Vp) {
  const int bid = blockIdx.x;
  if (bid < QK_BLOCKS) {
    const int idx = bid * 256 + threadIdx.x;
    const int kd = idx % 12;
    const int h  = (idx / 12) % 16;
    const int s  = (idx / 192) % S_TOT;
    const int p  = idx / (192 * S_TOT);
    const int seg = s >> 10, tb = (s >> 6) & 15, t = s & 63;
    short* out = (p ? Kp : Qp) +
                 ((size_t)(((seg * 16 + h) * 16 + tb) * 12 + kd) * 64 + t) * 8;
    short tmp[8];
    if (kd >= 10) {
      #pragma unroll
      for (int j = 0; j < 8; ++j) tmp[j] = 0;
      *(int4*)out = *(int4*)tmp;
      return;
    }
    const short* row = (const short*)qkv + (size_t)s * TDIM + p * DIM + h * HD;
    const int d0 = kd * 8;
    const v8s xm = *(const v8s*)(row + d0);
    const v8s xr = *(const v8s*)(row + d0 + ((kd < 5) ? 40 : -40));
    const float sgn = (kd < 5) ? -1.f : 1.f;
    const float scale = (p == 0) ? 0.111803398874989485f : 1.0f;
    #pragma unroll
    for (int j = 0; j < 8; ++j) {
      const int d = d0 + j;
      const float v = (bf2f(xm[j]) * cos_[s * HD + d] +
                       sgn * bf2f(xr[j]) * sin_[s * HD + d]) * scale;
      tmp[j] = f2bf(v);
    }
    *(int4*)out = *(int4*)tmp;
  } else {
    const int idx = (bid - QK_BLOCKS) * 256 + threadIdx.x;
    const int d  = idx % 96;
    const int td = (idx / 96) % 8;
    const int tb = (idx / 768) % 16;
    const int h  = (idx / (768 * 16)) % 16;
    const int seg = idx / (768 * 256);
    const int s0 = seg * SEG + tb * 64 + td * 8;
    const short* q = (const short*)qkv;
    short tmp[8];
    if (d < 80) {
      #pragma unroll
      for (int j = 0; j < 8; ++j)
        tmp[j] = q[(size_t)(s0 + j) * TDIM + 2 * DIM + h * HD + d];
    } else {
      const short fill = (d == 80) ? (short)0x3F80 : (short)0;
      #pragma unroll
      for (int j = 0; j < 8; ++j) tmp[j] = fill;
    }
    *(int4*)(Vp + (size_t)idx * 8) = *(int4*)tmp;
  }
}

// ---------------- fused flash MFMA attention (r14 version) ----------------
__global__ __launch_bounds__(256, 4) void attn_mfma(const short* __restrict__ Qp,
                                                    const short* __restrict__ Kp,
                                                    const short* __restrict__ Vp,
                                                    __hip_bfloat16* __restrict__ out) {
  __shared__ __align__(16) short Ks[64 * 96];
  __shared__ __align__(16) short Vs[64 * 96];
  __shared__ __align__(16) short Ps[4][16 * 68];

  const int qt  = blockIdx.x;
  const int h   = blockIdx.y;
  const int seg = blockIdx.z;
  const int tid  = threadIdx.x;
  const int wave = tid >> 6;
  const int lane = tid & 63;
  const int quad = lane >> 4;
  const int l16  = lane & 15;
  const int sh16 = seg * 16 + h;

  const short* Qg = Qp + (size_t)(sh16 * 16 + qt) * 6144;
  const short* Kg = Kp + (size_t)sh16 * 16 * 6144;
  const short* Vg = Vp + (size_t)sh16 * 16 * 6144;

  v8s af[3];
  #pragma unroll
  for (int ks = 0; ks < 3; ++ks)
    af[ks] = *(const v8s*)(Qg + ((ks * 4 + quad) * 64 + wave * 16 + l16) * 8);

  v8s kr[3], vr[3];
  #pragma unroll
  for (int it = 0; it < 3; ++it) {
    const int o = (it * 256 + tid) * 8;
    kr[it] = *(const v8s*)(Kg + o);
    vr[it] = *(const v8s*)(Vg + o);
  }
  #pragma unroll
  for (int it = 0; it < 3; ++it) {
    const int o = (it * 256 + tid) * 8;
    *(v8s*)&Ks[o] = kr[it];
    *(v8s*)&Vs[o] = vr[it];
  }
  __syncthreads();

  v4f o4[6];
  const v4f vz = {0.f, 0.f, 0.f, 0.f};
  #pragma unroll
  for (int n = 0; n < 6; ++n) o4[n] = vz;

  for (int kb = 0; kb < 16; ++kb) {
    const bool more = (kb + 1 < 16);
    if (more) {
      const size_t base = (size_t)(kb + 1) * 6144;
      #pragma unroll
      for (int it = 0; it < 3; ++it) {
        const int o = (it * 256 + tid) * 8;
        kr[it] = *(const v8s*)(Kg + base + o);
        vr[it] = *(const v8s*)(Vg + base + o);
      }
    }

    v4f s4[4];
    #pragma unroll
    for (int j = 0; j < 4; ++j) {
      s4[j] = vz;
      #pragma unroll
      for (int ks = 0; ks < 3; ++ks) {
        const v8s bf = *(const v8s*)&Ks[((ks * 4 + quad) * 64 + j * 16 + l16) * 8];
        s4[j] = __builtin_amdgcn_mfma_f32_16x16x32_bf16(af[ks], bf, s4[j], 0, 0, 0);
      }
    }

    #pragma unroll
    for (int reg = 0; reg < 4; ++reg)
      #pragma unroll
      for (int j = 0; j < 4; ++j)
        Ps[wave][(quad * 4 + reg) * 68 + j * 16 + l16] = f2bf(__expf(s4[j][reg]));

    v8s pa[2];
    #pragma unroll
    for (int kp = 0; kp < 2; ++kp)
      pa[kp] = *(const v8s*)&Ps[wave][l16 * 68 + kp * 32 + quad * 8];
    #pragma unroll
    for (int n = 0; n < 6; ++n) {
      #pragma unroll
      for (int kp = 0; kp < 2; ++kp) {
        const v8s vb = *(const v8s*)&Vs[((kp * 4 + quad) * 96 + n * 16 + l16) * 8];
        o4[n] = __builtin_amdgcn_mfma_f32_16x16x32_bf16(pa[kp], vb, o4[n], 0, 0, 0);
      }
    }

    __syncthreads();
    if (more) {
      #pragma unroll
      for (int it = 0; it < 3; ++it) {
        const int o = (it * 256 + tid) * 8;
        *(v8s*)&Ks[o] = kr[it];
        *(v8s*)&Vs[o] = vr[it];
      }
    }
    __syncthreads();
  }

  float inv[4];
  #pragma unroll
  for (int r = 0; r < 4; ++r)
    inv[r] = 1.f / __shfl(o4[5][r], quad << 4);
  const int row0 = seg * SEG + qt * 64 + wave * 16 + quad * 4;
  #pragma unroll
  for (int n = 0; n < 5; ++n) {
    const int col = h * HD + n * 16 + l16;
    #pragma unroll
    for (int r = 0; r < 4; ++r)
      out[(size_t)(row0 + r) * DIM + col] = __float2bfloat16(o4[n][r] * inv[r]);
  }
}

extern "C" void kernel_launch(void* const* d_in, const int* in_sizes, int n_in,
                              void* d_out, int out_size, void* d_ws, size_t ws_size,
                              hipStream_t stream) {
  (void)in_sizes; (void)n_in; (void)out_size; (void)ws_size;
  const float* hs     = (const float*)d_in[0];
  const float* cosp   = (const float*)d_in[1];
  const float* sinp   = (const float*)d_in[2];
  const float* qkv_w  = (const float*)d_in[3];
  const float* qkv_b  = (const float*)d_in[4];
  const float* proj_w = (const float*)d_in[5];
  const float* proj_b = (const float*)d_in[6];

  float* out_f = (float*)d_out;
  __hip_bfloat16* qkv_b16 = (__hip_bfloat16*)d_ws;                     // [A]
  __hip_bfloat16* hs_b    = qkv_b16 + (size_t)S_TOT * TDIM;            // [B]
  __hip_bfloat16* qkvw_b  = hs_b + (size_t)S_TOT * DIM;                // [C]
  __hip_bfloat16* projw_b = qkvw_b + (size_t)TDIM * DIM;               // [D]
  short* Qp = (short*)qkvw_b;                                          // alias [C]
  short* Kp = (short*)(projw_b + (size_t)DIM * DIM);                   // [E]
  short* Vp = Kp + (size_t)3 * 16 * 16 * 6144;                         // [F]
  __hip_bfloat16* attn_b = hs_b;                                       // alias [B]

  cvt3<<<(CVT_N1 + CVT_N2 + CVT_N3) / 256, 256, 0, stream>>>(
      hs, qkv_w, proj_w, hs_b, qkvw_b, projw_b);

  gemm1_c<<<dim3(S_TOT / 128, TDIM / 128), 256, 0, stream>>>(
      hs_b, qkvw_b, qkv_b, qkv_b16, S_TOT, TDIM, DIM);

  pack_all<<<QK_BLOCKS + V_BLOCKS, 256, 0, stream>>>(qkv_b16, cosp, sinp, Qp, Kp, Vp);

  attn_mfma<<<dim3(16, NH, 3), 256, 0, stream>>>(Qp, Kp, Vp, attn_b);

  gemm2_c<<<dim3(S_TOT / 64, DIM / 128), 256, 0, stream>>>(
      attn_b, projw_b, proj_b, out_f, S_TOT, DIM, DIM);
}